// Round 5
// baseline (126.041 us; speedup 1.0000x reference)
//
#include <hip/hip_runtime.h>
#include <hip/hip_bf16.h>

// Problem: B=4, H=W=64 -> N=4096 tokens, C=64, d=8
#define BATCH 4
#define NTOK 4096
#define CCH 64
#define KSPLIT 4
#define KPB (NTOK / KSPLIT)   // 1024 keys per attn block
#define NTILE (KPB / 64)      // 16 key tiles per attn block

typedef short s16x8 __attribute__((ext_vector_type(8)));
typedef float f32x4 __attribute__((ext_vector_type(4)));

static __device__ __forceinline__ unsigned short f2bf(float f) {
    union { __hip_bfloat16 h; unsigned short u; } cv;
    cv.h = __float2bfloat16(f);
    return cv.u;
}
static __device__ __forceinline__ float bf2f(unsigned short u) {
    union { unsigned int u; float f; } c; c.u = ((unsigned)u) << 16;
    return c.f;
}
// Dekker split: h = bf16(f) (RNE), returns exact residual f - h
static __device__ __forceinline__ float bf_split(float f, unsigned short& h) {
    h = f2bf(f);
    return f - bf2f(h);
}
// truncation pack: low short = bf16_trunc(a), high short = bf16_trunc(b)
static __device__ __forceinline__ unsigned pack_trunc(float a, float b) {
    union { float f; unsigned u; } ca, cb; ca.f = a; cb.f = b;
    return (ca.u >> 16) | (cb.u & 0xFFFF0000u);
}
// RNE pack
static __device__ __forceinline__ unsigned pack_rne(float a, float b) {
    return ((unsigned)f2bf(b) << 16) | f2bf(a);
}

// ---------------------------------------------------------------------------
// Projections (unchanged from R4).
//   Qpack[b][n][32] bf16 = [qh|ql|qh|0]   Kpack[b][n][32] bf16 = [kh|kh|kl|0]
//   vT[b][c][n] bf16 — V^T via MFMA
// ---------------------------------------------------------------------------
__global__ __launch_bounds__(256) void proj_kernel(
    const float* __restrict__ xg,
    const float* __restrict__ Wf, const float* __restrict__ bf_,
    const float* __restrict__ Wg, const float* __restrict__ bg,
    const float* __restrict__ Wh, const float* __restrict__ bh,
    unsigned short* __restrict__ Qp, unsigned short* __restrict__ Kp,
    unsigned short* __restrict__ vTg)
{
    __shared__ float xS[32 * 68];
    __shared__ float WfT[8 * 68];
    __shared__ float WgT[8 * 68];
    __shared__ unsigned short vtS[64 * 40];

    const int t = threadIdx.x;
    const int b = blockIdx.x >> 7;
    const int n0 = (blockIdx.x & 127) * 32;

    const float* xrow = xg + ((size_t)b * NTOK + n0) * CCH;
    for (int f = t; f < 512; f += 256) {
        int r = f >> 4, c4 = (f & 15) * 4;
        *(float4*)(xS + r * 68 + c4) = *(const float4*)(xrow + r * 64 + c4);
    }
    for (int e = t; e < 512; e += 256) {
        int ci = e >> 3, j = e & 7;
        WfT[j * 68 + ci] = Wf[e];
        WgT[j * 68 + ci] = Wg[e];
    }
    __syncthreads();

    const int w = t >> 6, lane = t & 63, ml = lane & 15, quad = lane >> 4;

    {
        s16x8 a0, a1;
        #pragma unroll
        for (int j = 0; j < 8; ++j) {
            a0[j] = (short)f2bf(Wh[(quad * 8 + j) * 64 + w * 16 + ml]);
            a1[j] = (short)f2bf(Wh[(32 + quad * 8 + j) * 64 + w * 16 + ml]);
        }
        #pragma unroll
        for (int nf = 0; nf < 2; ++nf) {
            int tok = nf * 16 + ml;
            float4 r0 = *(const float4*)(xS + tok * 68 + quad * 8);
            float4 r1 = *(const float4*)(xS + tok * 68 + quad * 8 + 4);
            float4 r2 = *(const float4*)(xS + tok * 68 + 32 + quad * 8);
            float4 r3 = *(const float4*)(xS + tok * 68 + 32 + quad * 8 + 4);
            s16x8 b0, b1;
            b0[0] = (short)f2bf(r0.x); b0[1] = (short)f2bf(r0.y);
            b0[2] = (short)f2bf(r0.z); b0[3] = (short)f2bf(r0.w);
            b0[4] = (short)f2bf(r1.x); b0[5] = (short)f2bf(r1.y);
            b0[6] = (short)f2bf(r1.z); b0[7] = (short)f2bf(r1.w);
            b1[0] = (short)f2bf(r2.x); b1[1] = (short)f2bf(r2.y);
            b1[2] = (short)f2bf(r2.z); b1[3] = (short)f2bf(r2.w);
            b1[4] = (short)f2bf(r3.x); b1[5] = (short)f2bf(r3.y);
            b1[6] = (short)f2bf(r3.z); b1[7] = (short)f2bf(r3.w);
            f32x4 cc = __builtin_amdgcn_mfma_f32_16x16x32_bf16(a0, b0, (f32x4){0.f,0.f,0.f,0.f}, 0, 0, 0);
            cc = __builtin_amdgcn_mfma_f32_16x16x32_bf16(a1, b1, cc, 0, 0, 0);
            #pragma unroll
            for (int reg = 0; reg < 4; ++reg) {
                int cout = w * 16 + quad * 4 + reg;
                vtS[cout * 40 + nf * 16 + ml] = f2bf(cc[reg] + bh[cout]);
            }
        }
    }

    {
        int r = t >> 3, j = t & 7;
        float q = bf_[j], k = bg[j];
        for (int ci = 0; ci < 64; ci += 4) {
            float4 x4 = *(const float4*)(xS + r * 68 + ci);
            float4 wf4 = *(const float4*)(WfT + j * 68 + ci);
            float4 wg4 = *(const float4*)(WgT + j * 68 + ci);
            q += x4.x * wf4.x + x4.y * wf4.y + x4.z * wf4.z + x4.w * wf4.w;
            k += x4.x * wg4.x + x4.y * wg4.y + x4.z * wg4.z + x4.w * wg4.w;
        }
        unsigned short qh, kh;
        float qres = bf_split(q, qh);
        float kres = bf_split(k, kh);
        unsigned short ql = f2bf(qres), kl = f2bf(kres);
        size_t base = ((size_t)b * NTOK + n0 + r) * 32;
        Qp[base + j]      = qh;
        Qp[base + 8 + j]  = ql;
        Qp[base + 16 + j] = qh;
        Qp[base + 24 + j] = 0;
        Kp[base + j]      = kh;
        Kp[base + 8 + j]  = kh;
        Kp[base + 16 + j] = kl;
        Kp[base + 24 + j] = 0;
    }
    __syncthreads();

    {
        int c_ = t >> 2, chunk = t & 3;
        uint4 v = *(const uint4*)(vtS + c_ * 40 + chunk * 8);
        *(uint4*)(vTg + ((size_t)b * CCH + c_) * NTOK + n0 + chunk * 8) = v;
    }
}

// ---------------------------------------------------------------------------
// Attention, register-resident P. grid = B*64*KSPLIT = 1024 blocks, 256 thr.
// Each wave owns 16 queries x all 64 channels. S^T-MFMA pair uses PERMUTED
// key rows (key_A(m)=8*(m>>2)+(m&3), key_B=key_A+4) so lane (ml,quad) ends
// holding keys 8*quad..8*quad+7 == exactly the PV B-operand layout. P never
// touches LDS; no barrier on the softmax path. K/V tiles are staged in
// double-buffered LDS (1 barrier/tile), global prefetch overlapped.
// ---------------------------------------------------------------------------
__global__ __launch_bounds__(256, 4) void attn_kernel(
    const unsigned short* __restrict__ Qp,
    const unsigned short* __restrict__ Kp,
    const unsigned short* __restrict__ vTg,
    unsigned short* __restrict__ Opart,
    float* __restrict__ lpart)
{
    __shared__ unsigned short VS[2][64 * 72];  // V^T tile [ch][key], stride 72
    __shared__ unsigned short KS[2][64 * 36];  // Kpack tile [key][32], stride 36

    const int t = threadIdx.x;
    const int blk = blockIdx.x;
    const int b = blk >> 8;
    const int qt = (blk >> 2) & 63;
    const int ks = blk & 3;
    const int m0 = qt * 64;
    const int kb0 = ks * KPB;
    const int w = t >> 6, lane = t & 63;
    const int ml = lane & 15, quad = lane >> 4;

    const unsigned short* qpb = Qp + (size_t)b * NTOK * 32;
    const unsigned short* kpb = Kp + (size_t)b * NTOK * 32;
    const unsigned short* vtb = vTg + (size_t)b * CCH * NTOK;

    // Q B-operand frag (queries w*16+ml), persists whole kernel
    const s16x8 qf = *(const s16x8*)(qpb + (size_t)(m0 + w * 16 + ml) * 32 + quad * 8);

    // permuted key row for the S-MFMA pair
    const int keyA = 8 * (ml >> 2) + (ml & 3);

    s16x8 ones;
    #pragma unroll
    for (int i = 0; i < 8; ++i) ones[i] = (short)0x3F80;

    f32x4 o[4];
    #pragma unroll
    for (int cg = 0; cg < 4; ++cg) o[cg] = (f32x4){0.f, 0.f, 0.f, 0.f};
    f32x4 lac = {0.f, 0.f, 0.f, 0.f};
    const f32x4 zz = {0.f, 0.f, 0.f, 0.f};

    // staging roles (per thread)
    const int vrow = t >> 2, vcb = (t & 3) * 2;   // V: channel row, 2x16B chunks
    const int krow = t >> 2, kpart = t & 3;       // K: key row, 1x16B chunk

    // ---- preload tile 0 into buf 0
    {
        uint4 va = *(const uint4*)(vtb + (size_t)vrow * NTOK + kb0 + vcb * 8);
        uint4 vb = *(const uint4*)(vtb + (size_t)vrow * NTOK + kb0 + (vcb + 1) * 8);
        uint4 kk = *(const uint4*)(kpb + (size_t)(kb0 + krow) * 32 + kpart * 8);
        *(uint4*)(&VS[0][vrow * 72 + vcb * 8]) = va;
        *(uint4*)(&VS[0][vrow * 72 + (vcb + 1) * 8]) = vb;
        *(uint4*)(&KS[0][krow * 36 + kpart * 8]) = kk;
    }

    for (int jt = 0; jt < NTILE; ++jt) {
        const int buf = jt & 1;
        __syncthreads();   // tile jt's K/V LDS ready; prev reads done

        // K A-frags from LDS (permuted rows): pair (A,B) per 32-key step
        const unsigned short* ksb = &KS[buf][0];
        s16x8 kf0 = *(const s16x8*)(ksb + (keyA) * 36 + quad * 8);
        s16x8 kf1 = *(const s16x8*)(ksb + (keyA + 4) * 36 + quad * 8);
        s16x8 kf2 = *(const s16x8*)(ksb + (32 + keyA) * 36 + quad * 8);
        s16x8 kf3 = *(const s16x8*)(ksb + (32 + keyA + 4) * 36 + quad * 8);

        // S^T: lane (ml,quad) reg r = s(key, query ml)
        f32x4 sA0 = __builtin_amdgcn_mfma_f32_16x16x32_bf16(kf0, qf, zz, 0, 0, 0);
        f32x4 sB0 = __builtin_amdgcn_mfma_f32_16x16x32_bf16(kf1, qf, zz, 0, 0, 0);
        f32x4 sA1 = __builtin_amdgcn_mfma_f32_16x16x32_bf16(kf2, qf, zz, 0, 0, 0);
        f32x4 sB1 = __builtin_amdgcn_mfma_f32_16x16x32_bf16(kf3, qf, zz, 0, 0, 0);

        // global prefetch tile jt+1 (overlaps exp chain)
        uint4 va, vb, kk;
        const bool more = (jt + 1 < NTILE);
        if (more) {
            const int kbn = kb0 + (jt + 1) * 64;
            va = *(const uint4*)(vtb + (size_t)vrow * NTOK + kbn + vcb * 8);
            vb = *(const uint4*)(vtb + (size_t)vrow * NTOK + kbn + (vcb + 1) * 8);
            kk = *(const uint4*)(kpb + (size_t)(kbn + krow) * 32 + kpart * 8);
        }

        // p = exp2(s*log2e - 20*log2e); pack directly into PV B-frags.
        // bfrag element j of lane (ml,quad) = key 8*quad+j  (by construction)
        union { unsigned u[4]; s16x8 h; } bf0, bf1;
        bf0.u[0] = pack_trunc(exp2f(fmaf(sA0[0], 1.442695041f, -28.85390082f)),
                              exp2f(fmaf(sA0[1], 1.442695041f, -28.85390082f)));
        bf0.u[1] = pack_trunc(exp2f(fmaf(sA0[2], 1.442695041f, -28.85390082f)),
                              exp2f(fmaf(sA0[3], 1.442695041f, -28.85390082f)));
        bf0.u[2] = pack_trunc(exp2f(fmaf(sB0[0], 1.442695041f, -28.85390082f)),
                              exp2f(fmaf(sB0[1], 1.442695041f, -28.85390082f)));
        bf0.u[3] = pack_trunc(exp2f(fmaf(sB0[2], 1.442695041f, -28.85390082f)),
                              exp2f(fmaf(sB0[3], 1.442695041f, -28.85390082f)));
        bf1.u[0] = pack_trunc(exp2f(fmaf(sA1[0], 1.442695041f, -28.85390082f)),
                              exp2f(fmaf(sA1[1], 1.442695041f, -28.85390082f)));
        bf1.u[1] = pack_trunc(exp2f(fmaf(sA1[2], 1.442695041f, -28.85390082f)),
                              exp2f(fmaf(sA1[3], 1.442695041f, -28.85390082f)));
        bf1.u[2] = pack_trunc(exp2f(fmaf(sB1[0], 1.442695041f, -28.85390082f)),
                              exp2f(fmaf(sB1[1], 1.442695041f, -28.85390082f)));
        bf1.u[3] = pack_trunc(exp2f(fmaf(sB1[2], 1.442695041f, -28.85390082f)),
                              exp2f(fmaf(sB1[3], 1.442695041f, -28.85390082f)));

        // write prefetched tile jt+1 into the other buffer (safe: post-barrier)
        if (more) {
            *(uint4*)(&VS[buf ^ 1][vrow * 72 + vcb * 8]) = va;
            *(uint4*)(&VS[buf ^ 1][vrow * 72 + (vcb + 1) * 8]) = vb;
            *(uint4*)(&KS[buf ^ 1][krow * 36 + kpart * 8]) = kk;
        }

        // l += ones * P   (row-sum over this tile's 64 keys, col = query ml)
        lac = __builtin_amdgcn_mfma_f32_16x16x32_bf16(ones, bf0.h, lac, 0, 0, 0);
        lac = __builtin_amdgcn_mfma_f32_16x16x32_bf16(ones, bf1.h, lac, 0, 0, 0);

        // O^T += V^T * P : A = V^T channels cg*16.., keys of this tile
        const unsigned short* vs = &VS[buf][0];
        #pragma unroll
        for (int cg = 0; cg < 4; ++cg) {
            s16x8 vA0 = *(const s16x8*)(vs + (cg * 16 + ml) * 72 + quad * 8);
            s16x8 vA1 = *(const s16x8*)(vs + (cg * 16 + ml) * 72 + 32 + quad * 8);
            o[cg] = __builtin_amdgcn_mfma_f32_16x16x32_bf16(vA0, bf0.h, o[cg], 0, 0, 0);
            o[cg] = __builtin_amdgcn_mfma_f32_16x16x32_bf16(vA1, bf1.h, o[cg], 0, 0, 0);
        }
    }

    // ---- epilogue: transpose O^T (row=channel, col=query) via LDS, store
    if (quad == 0)
        lpart[ks * (BATCH * NTOK) + b * NTOK + m0 + w * 16 + ml] = lac[0];

    __syncthreads();  // all VS reads done; reuse VS[0] as transpose buffer
    unsigned short* TR = &VS[0][0];  // [query 64][ch 64], stride 72
    #pragma unroll
    for (int cg = 0; cg < 4; ++cg) {
        uint2 dd = { pack_rne(o[cg][0], o[cg][1]), pack_rne(o[cg][2], o[cg][3]) };
        *(uint2*)(&TR[(w * 16 + ml) * 72 + cg * 16 + quad * 4]) = dd;
    }
    __syncthreads();
    {
        int ql = t >> 2, ch = t & 3;
        uint4 u0 = *(const uint4*)(&TR[ql * 72 + ch * 16]);
        uint4 u1 = *(const uint4*)(&TR[ql * 72 + ch * 16 + 8]);
        size_t obase = ((size_t)ks * (BATCH * NTOK) + (size_t)b * NTOK + m0 + ql) * 64;
        *(uint4*)(Opart + obase + ch * 16) = u0;
        *(uint4*)(Opart + obase + ch * 16 + 8) = u1;
    }
}

// ---------------------------------------------------------------------------
// Combine: out = gamma * (sum_s O_s) / (sum_s l_s) + x.  1024 blocks x 256.
// ---------------------------------------------------------------------------
__global__ __launch_bounds__(256) void combine_kernel(
    const float* __restrict__ xg,
    const unsigned short* __restrict__ Opart,
    const float* __restrict__ lpart,
    const float* __restrict__ gammaPtr,
    float* __restrict__ out)
{
    const int i4 = blockIdx.x * 256 + threadIdx.x;
    const int base = i4 * 4;
    const int tok = base >> 6;

    float lsum = 0.f;
    #pragma unroll
    for (int s = 0; s < KSPLIT; ++s)
        lsum += lpart[s * (BATCH * NTOK) + tok];

    float o0 = 0.f, o1 = 0.f, o2 = 0.f, o3 = 0.f;
    #pragma unroll
    for (int s = 0; s < KSPLIT; ++s) {
        uint2 u = *(const uint2*)(Opart + (size_t)s * (BATCH * NTOK * 64) + base);
        o0 += bf2f((unsigned short)(u.x & 0xFFFF));
        o1 += bf2f((unsigned short)(u.x >> 16));
        o2 += bf2f((unsigned short)(u.y & 0xFFFF));
        o3 += bf2f((unsigned short)(u.y >> 16));
    }
    const float4 x4 = *(const float4*)(xg + base);
    const float gi = gammaPtr[0] / lsum;
    float4 r;
    r.x = gi * o0 + x4.x;
    r.y = gi * o1 + x4.y;
    r.z = gi * o2 + x4.z;
    r.w = gi * o3 + x4.w;
    *(float4*)(out + base) = r;
}

extern "C" void kernel_launch(void* const* d_in, const int* in_sizes, int n_in,
                              void* d_out, int out_size, void* d_ws, size_t ws_size,
                              hipStream_t stream) {
    const float* x  = (const float*)d_in[0];
    const float* Wf = (const float*)d_in[1];
    const float* bf = (const float*)d_in[2];
    const float* Wg = (const float*)d_in[3];
    const float* bg = (const float*)d_in[4];
    const float* Wh = (const float*)d_in[5];
    const float* bh = (const float*)d_in[6];
    const float* gamma = (const float*)d_in[7];
    float* out = (float*)d_out;

    // ws: Qp 1MB | Kp 1MB | vT 2MB | Opart 8MB | lpart 256KB
    char* ws = (char*)d_ws;
    unsigned short* Qp    = (unsigned short*)ws;
    unsigned short* Kp    = (unsigned short*)(ws + (1u << 20));
    unsigned short* vTg   = (unsigned short*)(ws + (2u << 20));
    unsigned short* Opart = (unsigned short*)(ws + (4u << 20));
    float*          lpart = (float*)(ws + (12u << 20));

    proj_kernel<<<BATCH * 128, 256, 0, stream>>>(x, Wf, bf, Wg, bg, Wh, bh,
                                                 Qp, Kp, vTg);
    attn_kernel<<<BATCH * 64 * KSPLIT, 256, 0, stream>>>(Qp, Kp, vTg, Opart, lpart);
    combine_kernel<<<(BATCH * NTOK * CCH) / 1024, 256, 0, stream>>>(x, Opart, lpart, gamma, out);
}

// Round 7
// 111.141 us; speedup vs baseline: 1.1341x; 1.1341x over previous
//
#include <hip/hip_runtime.h>
#include <hip/hip_bf16.h>

// Problem: B=4, H=W=64 -> N=4096 tokens, C=64, d=8
#define BATCH 4
#define NTOK 4096
#define CCH 64
#define KSPLIT 8
#define KPB (NTOK / KSPLIT)   // 512 keys per attn block
#define NTILE (KPB / 64)      // 8 key tiles per attn block

typedef short s16x8 __attribute__((ext_vector_type(8)));
typedef float f32x4 __attribute__((ext_vector_type(4)));

#define LOG2E 1.442695041f
#define ESHIFT (-28.85390082f)   // -20 * log2(e)

static __device__ __forceinline__ unsigned short f2bf(float f) {
    union { __hip_bfloat16 h; unsigned short u; } cv;
    cv.h = __float2bfloat16(f);
    return cv.u;
}
static __device__ __forceinline__ float bf2f(unsigned short u) {
    union { unsigned int u; float f; } c; c.u = ((unsigned)u) << 16;
    return c.f;
}
static __device__ __forceinline__ float bf_split(float f, unsigned short& h) {
    h = f2bf(f);
    return f - bf2f(h);
}
static __device__ __forceinline__ unsigned pack_trunc(float a, float b) {
    union { float f; unsigned u; } ca, cb; ca.f = a; cb.f = b;
    return (ca.u >> 16) | (cb.u & 0xFFFF0000u);
}
static __device__ __forceinline__ unsigned pack_rne(float a, float b) {
    return ((unsigned)f2bf(b) << 16) | f2bf(a);
}
static __device__ __forceinline__ float pexp(float s) {
    return exp2f(fmaf(s, LOG2E, ESHIFT));
}

// ---------------------------------------------------------------------------
// Projections.
//   Qpack[b][n][32] bf16 = [qh|ql|qh|0]   Kpack[b][n][32] bf16 = [kh|kh|kl|0]
//   vT[b][c][n] bf16 — V^T via MFMA (bf16 x staged once in LDS)
// grid: B*128 blocks (32-token tiles), 256 threads.
// ---------------------------------------------------------------------------
__global__ __launch_bounds__(256) void proj_kernel(
    const float* __restrict__ xg,
    const float* __restrict__ Wf, const float* __restrict__ bf_,
    const float* __restrict__ Wg, const float* __restrict__ bg,
    const float* __restrict__ Wh, const float* __restrict__ bh,
    unsigned short* __restrict__ Qp, unsigned short* __restrict__ Kp,
    unsigned short* __restrict__ vTg)
{
    __shared__ float xS[32 * 68];            // fp32 x tile (q/k path)
    __shared__ unsigned short xbS[32 * 72];  // bf16 x tile, 64 ch/row, stride 72
    __shared__ float WfT[8 * 68];
    __shared__ float WgT[8 * 68];
    __shared__ unsigned short vtS[64 * 40];  // V^T tile [cout][32 tok + pad]

    const int t = threadIdx.x;
    const int b = blockIdx.x >> 7;
    const int n0 = (blockIdx.x & 127) * 32;

    const float* xrow = xg + ((size_t)b * NTOK + n0) * CCH;
    for (int f = t; f < 512; f += 256) {
        int r = f >> 4, c4 = (f & 15) * 4;
        float4 v = *(const float4*)(xrow + r * 64 + c4);
        *(float4*)(xS + r * 68 + c4) = v;
        uint2 pk = { pack_rne(v.x, v.y), pack_rne(v.z, v.w) };
        *(uint2*)(xbS + r * 72 + c4) = pk;
    }
    for (int e = t; e < 512; e += 256) {
        int ci = e >> 3, j = e & 7;
        WfT[j * 68 + ci] = Wf[e];
        WgT[j * 68 + ci] = Wg[e];
    }
    __syncthreads();

    const int w = t >> 6, lane = t & 63, ml = lane & 15, quad = lane >> 4;

    // ---- V^T via MFMA: wave w owns couts w*16..w*16+15
    {
        s16x8 a0, a1;   // A[m=cout][k=cin] = Wh[cin][cout]
        #pragma unroll
        for (int j = 0; j < 8; ++j) {
            a0[j] = (short)f2bf(Wh[(quad * 8 + j) * 64 + w * 16 + ml]);
            a1[j] = (short)f2bf(Wh[(32 + quad * 8 + j) * 64 + w * 16 + ml]);
        }
        #pragma unroll
        for (int nf = 0; nf < 2; ++nf) {
            int tok = nf * 16 + ml;
            s16x8 b0 = *(const s16x8*)(xbS + tok * 72 + quad * 8);
            s16x8 b1 = *(const s16x8*)(xbS + tok * 72 + 32 + quad * 8);
            f32x4 cc = __builtin_amdgcn_mfma_f32_16x16x32_bf16(a0, b0, (f32x4){0.f,0.f,0.f,0.f}, 0, 0, 0);
            cc = __builtin_amdgcn_mfma_f32_16x16x32_bf16(a1, b1, cc, 0, 0, 0);
            #pragma unroll
            for (int reg = 0; reg < 4; ++reg) {
                int cout = w * 16 + quad * 4 + reg;
                vtS[cout * 40 + nf * 16 + ml] = f2bf(cc[reg] + bh[cout]);
            }
        }
    }

    // ---- q/k: thread (r = t>>3, j = t&7): fp32 VALU + Dekker pack
    {
        int r = t >> 3, j = t & 7;
        float q = bf_[j], k = bg[j];
        for (int ci = 0; ci < 64; ci += 4) {
            float4 x4 = *(const float4*)(xS + r * 68 + ci);
            float4 wf4 = *(const float4*)(WfT + j * 68 + ci);
            float4 wg4 = *(const float4*)(WgT + j * 68 + ci);
            q += x4.x * wf4.x + x4.y * wf4.y + x4.z * wf4.z + x4.w * wf4.w;
            k += x4.x * wg4.x + x4.y * wg4.y + x4.z * wg4.z + x4.w * wg4.w;
        }
        unsigned short qh, kh;
        float qres = bf_split(q, qh);
        float kres = bf_split(k, kh);
        unsigned short ql = f2bf(qres), kl = f2bf(kres);
        size_t base = ((size_t)b * NTOK + n0 + r) * 32;
        Qp[base + j]      = qh;
        Qp[base + 8 + j]  = ql;
        Qp[base + 16 + j] = qh;
        Qp[base + 24 + j] = 0;
        Kp[base + j]      = kh;
        Kp[base + 8 + j]  = kh;
        Kp[base + 16 + j] = kl;
        Kp[base + 24 + j] = 0;
    }
    __syncthreads();

    // ---- coalesced vT store
    {
        int c_ = t >> 2, chunk = t & 3;
        uint4 v = *(const uint4*)(vtS + c_ * 40 + chunk * 8);
        *(uint4*)(vTg + ((size_t)b * CCH + c_) * NTOK + n0 + chunk * 8) = v;
    }
}

// ---------------------------------------------------------------------------
// Attention, register-resident P, K resident in LDS.
// grid = B * 64 qtiles * KSPLIT(8) = 2048 blocks, 256 threads, 3 blocks/CU.
// KC[key][24] = [kh8|kl8|zero8] staged ONCE (static after init barrier) ->
// K-frags prefetched one tile ahead with NO barrier on the S path.
// V^T double-buffered in LDS, ONE barrier per tile.
// P: S^T-MFMA with permuted key rows (keyA = 8*(m>>2)+(m&3)) lands exp(P)
// directly in PV B-operand layout; never touches LDS.
// ---------------------------------------------------------------------------
__global__ __launch_bounds__(256, 3) void attn_kernel(
    const unsigned short* __restrict__ Qp,
    const unsigned short* __restrict__ Kp,
    const unsigned short* __restrict__ vTg,
    unsigned short* __restrict__ Opart,
    float* __restrict__ lpart)
{
    __shared__ unsigned short KC[KPB * 24];    // [key][kh8|kl8|zero8], 24 KB
    __shared__ unsigned short VS[2][64 * 72];  // V^T tile [ch][key], 18.4 KB

    const int t = threadIdx.x;
    const int blk = blockIdx.x;
    const int b = blk >> 9;
    const int qt = (blk >> 3) & 63;
    const int ks = blk & 7;
    const int m0 = qt * 64;
    const int kb0 = ks * KPB;
    const int w = t >> 6, lane = t & 63;
    const int ml = lane & 15, quad = lane >> 4;

    const unsigned short* qpb = Qp + (size_t)b * NTOK * 32;
    const unsigned short* kpb = Kp + (size_t)b * NTOK * 32;
    const unsigned short* vtb = vTg + (size_t)b * CCH * NTOK;

    // Q B-operand frag (queries m0 + w*16 + ml), persists whole kernel
    const s16x8 qf = *(const s16x8*)(qpb + (size_t)(m0 + w * 16 + ml) * 32 + quad * 8);

    const int keyA = 8 * (ml >> 2) + (ml & 3);              // permuted key row
    const int sel = (quad < 2) ? 0 : (quad == 2 ? 8 : 16);  // kh|kh|kl|0 select

    s16x8 ones;
    #pragma unroll
    for (int i = 0; i < 8; ++i) ones[i] = (short)0x3F80;

    f32x4 o[4];
    #pragma unroll
    for (int cg = 0; cg < 4; ++cg) o[cg] = (f32x4){0.f, 0.f, 0.f, 0.f};
    f32x4 lac = {0.f, 0.f, 0.f, 0.f};
    const f32x4 zz = {0.f, 0.f, 0.f, 0.f};

    // ---- stage KC (compact K) for all 512 keys of this split
    for (int kk = t; kk < KPB; kk += 256) {
        const unsigned short* src = kpb + (size_t)(kb0 + kk) * 32;
        uint4 khh = *(const uint4*)(src);        // kh (shorts 0..7)
        uint4 kll = *(const uint4*)(src + 16);   // kl (shorts 16..23)
        *(uint4*)(&KC[kk * 24 + 0]) = khh;
        *(uint4*)(&KC[kk * 24 + 8]) = kll;
        *(uint4*)(&KC[kk * 24 + 16]) = make_uint4(0u, 0u, 0u, 0u);
    }
    // ---- stage V tile 0 into buf 0
    const int vrow = t >> 2, vcb = (t & 3) * 2;
    {
        uint4 va = *(const uint4*)(vtb + (size_t)vrow * NTOK + kb0 + vcb * 8);
        uint4 vb = *(const uint4*)(vtb + (size_t)vrow * NTOK + kb0 + (vcb + 1) * 8);
        *(uint4*)(&VS[0][vrow * 72 + vcb * 8]) = va;
        *(uint4*)(&VS[0][vrow * 72 + (vcb + 1) * 8]) = vb;
    }
    __syncthreads();   // KC + V0 visible

    // preload K frags for tile 0 (LDS, static region)
    s16x8 kf0 = *(const s16x8*)(&KC[(keyA) * 24 + sel]);
    s16x8 kf1 = *(const s16x8*)(&KC[(keyA + 4) * 24 + sel]);
    s16x8 kf2 = *(const s16x8*)(&KC[(32 + keyA) * 24 + sel]);
    s16x8 kf3 = *(const s16x8*)(&KC[(36 + keyA) * 24 + sel]);

    for (int jt = 0; jt < NTILE; ++jt) {
        const int buf = jt & 1;
        __syncthreads();   // VS[buf] (tile jt) visible; prior reads of VS[buf^1] retired

        // S^T from register K frags (no LDS dependency)
        f32x4 sA0 = __builtin_amdgcn_mfma_f32_16x16x32_bf16(kf0, qf, zz, 0, 0, 0);
        f32x4 sB0 = __builtin_amdgcn_mfma_f32_16x16x32_bf16(kf1, qf, zz, 0, 0, 0);
        f32x4 sA1 = __builtin_amdgcn_mfma_f32_16x16x32_bf16(kf2, qf, zz, 0, 0, 0);
        f32x4 sB1 = __builtin_amdgcn_mfma_f32_16x16x32_bf16(kf3, qf, zz, 0, 0, 0);

        // V frags for tile jt (consumed after the exp chain)
        const unsigned short* vs = &VS[buf][0];
        s16x8 vA0 = *(const s16x8*)(vs + (0 * 16 + ml) * 72 + quad * 8);
        s16x8 vB0 = *(const s16x8*)(vs + (0 * 16 + ml) * 72 + 32 + quad * 8);
        s16x8 vA1 = *(const s16x8*)(vs + (1 * 16 + ml) * 72 + quad * 8);
        s16x8 vB1 = *(const s16x8*)(vs + (1 * 16 + ml) * 72 + 32 + quad * 8);
        s16x8 vA2 = *(const s16x8*)(vs + (2 * 16 + ml) * 72 + quad * 8);
        s16x8 vB2 = *(const s16x8*)(vs + (2 * 16 + ml) * 72 + 32 + quad * 8);
        s16x8 vA3 = *(const s16x8*)(vs + (3 * 16 + ml) * 72 + quad * 8);
        s16x8 vB3 = *(const s16x8*)(vs + (3 * 16 + ml) * 72 + 32 + quad * 8);

        // global fetch of V tile jt+1 (issued early, written to other buf later)
        const bool more = (jt + 1 < NTILE);
        uint4 va, vb;
        if (more) {
            const int kbn = kb0 + (jt + 1) * 64;
            va = *(const uint4*)(vtb + (size_t)vrow * NTOK + kbn + vcb * 8);
            vb = *(const uint4*)(vtb + (size_t)vrow * NTOK + kbn + (vcb + 1) * 8);
        }
        // prefetch K frags for tile jt+1 (static LDS, no barrier needed)
        {
            const int kloc = (more ? (jt + 1) : 0) * 64;
            kf0 = *(const s16x8*)(&KC[(kloc + keyA) * 24 + sel]);
            kf1 = *(const s16x8*)(&KC[(kloc + keyA + 4) * 24 + sel]);
            kf2 = *(const s16x8*)(&KC[(kloc + 32 + keyA) * 24 + sel]);
            kf3 = *(const s16x8*)(&KC[(kloc + 36 + keyA) * 24 + sel]);
        }

        // p = exp(s - 20) -> bf16, packed straight into PV B-operand frags
        union { unsigned u[4]; s16x8 h; } bf0, bf1;
        bf0.u[0] = pack_trunc(pexp(sA0[0]), pexp(sA0[1]));
        bf0.u[1] = pack_trunc(pexp(sA0[2]), pexp(sA0[3]));
        bf0.u[2] = pack_trunc(pexp(sB0[0]), pexp(sB0[1]));
        bf0.u[3] = pack_trunc(pexp(sB0[2]), pexp(sB0[3]));
        bf1.u[0] = pack_trunc(pexp(sA1[0]), pexp(sA1[1]));
        bf1.u[1] = pack_trunc(pexp(sA1[2]), pexp(sA1[3]));
        bf1.u[2] = pack_trunc(pexp(sB1[0]), pexp(sB1[1]));
        bf1.u[3] = pack_trunc(pexp(sB1[2]), pexp(sB1[3]));

        // stage V tile jt+1 into the other buffer (post-barrier: hazard-free)
        if (more) {
            *(uint4*)(&VS[buf ^ 1][vrow * 72 + vcb * 8]) = va;
            *(uint4*)(&VS[buf ^ 1][vrow * 72 + (vcb + 1) * 8]) = vb;
        }

        // l += ones * P  (row-sum over tile's 64 keys; col = query ml)
        lac = __builtin_amdgcn_mfma_f32_16x16x32_bf16(ones, bf0.h, lac, 0, 0, 0);
        lac = __builtin_amdgcn_mfma_f32_16x16x32_bf16(ones, bf1.h, lac, 0, 0, 0);

        // O^T += V^T * P
        o[0] = __builtin_amdgcn_mfma_f32_16x16x32_bf16(vA0, bf0.h, o[0], 0, 0, 0);
        o[0] = __builtin_amdgcn_mfma_f32_16x16x32_bf16(vB0, bf1.h, o[0], 0, 0, 0);
        o[1] = __builtin_amdgcn_mfma_f32_16x16x32_bf16(vA1, bf0.h, o[1], 0, 0, 0);
        o[1] = __builtin_amdgcn_mfma_f32_16x16x32_bf16(vB1, bf1.h, o[1], 0, 0, 0);
        o[2] = __builtin_amdgcn_mfma_f32_16x16x32_bf16(vA2, bf0.h, o[2], 0, 0, 0);
        o[2] = __builtin_amdgcn_mfma_f32_16x16x32_bf16(vB2, bf1.h, o[2], 0, 0, 0);
        o[3] = __builtin_amdgcn_mfma_f32_16x16x32_bf16(vA3, bf0.h, o[3], 0, 0, 0);
        o[3] = __builtin_amdgcn_mfma_f32_16x16x32_bf16(vB3, bf1.h, o[3], 0, 0, 0);
    }

    // ---- epilogue
    if (quad == 0)
        lpart[ks * (BATCH * NTOK) + b * NTOK + m0 + w * 16 + ml] = lac[0];

    // transpose O^T (row=channel, col=query) via VS[0] (safe: last tile used VS[1])
    unsigned short* TR = &VS[0][0];   // [query 64][ch 64], stride 72
    #pragma unroll
    for (int cg = 0; cg < 4; ++cg) {
        uint2 dd = { pack_rne(o[cg][0], o[cg][1]), pack_rne(o[cg][2], o[cg][3]) };
        *(uint2*)(&TR[(w * 16 + ml) * 72 + cg * 16 + quad * 4]) = dd;
    }
    __syncthreads();
    {
        int ql = t >> 2, ch = t & 3;
        uint4 u0 = *(const uint4*)(&TR[ql * 72 + ch * 16]);
        uint4 u1 = *(const uint4*)(&TR[ql * 72 + ch * 16 + 8]);
        size_t obase = ((size_t)ks * (BATCH * NTOK) + (size_t)b * NTOK + m0 + ql) * 64;
        *(uint4*)(Opart + obase + ch * 16) = u0;
        *(uint4*)(Opart + obase + ch * 16 + 8) = u1;
    }
}

// ---------------------------------------------------------------------------
// Combine: out = gamma * (sum_s O_s) / (sum_s l_s) + x.  1024 blocks x 256.
// ---------------------------------------------------------------------------
__global__ __launch_bounds__(256) void combine_kernel(
    const float* __restrict__ xg,
    const unsigned short* __restrict__ Opart,
    const float* __restrict__ lpart,
    const float* __restrict__ gammaPtr,
    float* __restrict__ out)
{
    const int i4 = blockIdx.x * 256 + threadIdx.x;
    const int base = i4 * 4;
    const int tok = base >> 6;

    float lsum = 0.f;
    #pragma unroll
    for (int s = 0; s < KSPLIT; ++s)
        lsum += lpart[s * (BATCH * NTOK) + tok];

    float o0 = 0.f, o1 = 0.f, o2 = 0.f, o3 = 0.f;
    #pragma unroll
    for (int s = 0; s < KSPLIT; ++s) {
        uint2 u = *(const uint2*)(Opart + (size_t)s * (BATCH * NTOK * 64) + base);
        o0 += bf2f((unsigned short)(u.x & 0xFFFF));
        o1 += bf2f((unsigned short)(u.x >> 16));
        o2 += bf2f((unsigned short)(u.y & 0xFFFF));
        o3 += bf2f((unsigned short)(u.y >> 16));
    }
    const float4 x4 = *(const float4*)(xg + base);
    const float gi = gammaPtr[0] / lsum;
    float4 r;
    r.x = gi * o0 + x4.x;
    r.y = gi * o1 + x4.y;
    r.z = gi * o2 + x4.z;
    r.w = gi * o3 + x4.w;
    *(float4*)(out + base) = r;
}

extern "C" void kernel_launch(void* const* d_in, const int* in_sizes, int n_in,
                              void* d_out, int out_size, void* d_ws, size_t ws_size,
                              hipStream_t stream) {
    const float* x  = (const float*)d_in[0];
    const float* Wf = (const float*)d_in[1];
    const float* bf = (const float*)d_in[2];
    const float* Wg = (const float*)d_in[3];
    const float* bg = (const float*)d_in[4];
    const float* Wh = (const float*)d_in[5];
    const float* bh = (const float*)d_in[6];
    const float* gamma = (const float*)d_in[7];
    float* out = (float*)d_out;

    // ws: Qp 1MB @0 | Kp 1MB @1MB | vT 2MB @2MB | Opart 16MB @4MB | lpart @20MB
    char* ws = (char*)d_ws;
    unsigned short* Qp    = (unsigned short*)ws;
    unsigned short* Kp    = (unsigned short*)(ws + (1u << 20));
    unsigned short* vTg   = (unsigned short*)(ws + (2u << 20));
    unsigned short* Opart = (unsigned short*)(ws + (4u << 20));
    float*          lpart = (float*)(ws + (20u << 20));

    proj_kernel<<<BATCH * 128, 256, 0, stream>>>(x, Wf, bf, Wg, bg, Wh, bh,
                                                 Qp, Kp, vTg);
    attn_kernel<<<BATCH * 64 * KSPLIT, 256, 0, stream>>>(Qp, Kp, vTg, Opart, lpart);
    combine_kernel<<<(BATCH * NTOK * CCH) / 1024, 256, 0, stream>>>(x, Opart, lpart, gamma, out);
}

// Round 8
// 111.078 us; speedup vs baseline: 1.1347x; 1.0006x over previous
//
#include <hip/hip_runtime.h>
#include <hip/hip_bf16.h>

// Problem: B=4, H=W=64 -> N=4096 tokens, C=64, d=8
#define BATCH 4
#define NTOK 4096
#define CCH 64
#define KSPLIT 2
#define KPB (NTOK / KSPLIT)   // 2048 keys per attn block
#define NTILE (KPB / 64)      // 32 key tiles per block
#define TPW (NTILE / 4)       // 8 tiles per wave (waves own disjoint tiles)

typedef short s16x8 __attribute__((ext_vector_type(8)));
typedef float f32x4 __attribute__((ext_vector_type(4)));

#define LOG2E 1.442695041f
#define ESHIFT (-28.85390082f)   // -20 * log2(e)

static __device__ __forceinline__ unsigned short f2bf(float f) {
    union { __hip_bfloat16 h; unsigned short u; } cv;
    cv.h = __float2bfloat16(f);
    return cv.u;
}
static __device__ __forceinline__ float bf2f(unsigned short u) {
    union { unsigned int u; float f; } c; c.u = ((unsigned)u) << 16;
    return c.f;
}
static __device__ __forceinline__ float bf_split(float f, unsigned short& h) {
    h = f2bf(f);
    return f - bf2f(h);
}
static __device__ __forceinline__ unsigned pack_trunc(float a, float b) {
    union { float f; unsigned u; } ca, cb; ca.f = a; cb.f = b;
    return (ca.u >> 16) | (cb.u & 0xFFFF0000u);
}
static __device__ __forceinline__ unsigned pack_rne(float a, float b) {
    return ((unsigned)f2bf(b) << 16) | f2bf(a);
}
static __device__ __forceinline__ float pexp(float s) {
    return exp2f(fmaf(s, LOG2E, ESHIFT));
}

// ---------------------------------------------------------------------------
// Projections.
//   Qpack[b][n][32] bf16 = [qh|ql|qh|0]
//   Kpack[b][n][16] bf16 = [kh|kl]           (quad3 A-slice multiplies Q's
//                                             zero slice, so no zero pad)
//   vT[b][c][n] bf16 — V^T via MFMA (bf16 x staged once in LDS)
// grid: B*128 blocks (32-token tiles), 256 threads.
// ---------------------------------------------------------------------------
__global__ __launch_bounds__(256) void proj_kernel(
    const float* __restrict__ xg,
    const float* __restrict__ Wf, const float* __restrict__ bf_,
    const float* __restrict__ Wg, const float* __restrict__ bg,
    const float* __restrict__ Wh, const float* __restrict__ bh,
    unsigned short* __restrict__ Qp, unsigned short* __restrict__ Kp,
    unsigned short* __restrict__ vTg)
{
    __shared__ float xS[32 * 68];            // fp32 x tile (q/k path)
    __shared__ unsigned short xbS[32 * 72];  // bf16 x tile, 64 ch/row
    __shared__ float WfT[8 * 68];
    __shared__ float WgT[8 * 68];
    __shared__ unsigned short vtS[64 * 40];  // V^T tile [cout][32 tok + pad]

    const int t = threadIdx.x;
    const int b = blockIdx.x >> 7;
    const int n0 = (blockIdx.x & 127) * 32;

    const float* xrow = xg + ((size_t)b * NTOK + n0) * CCH;
    for (int f = t; f < 512; f += 256) {
        int r = f >> 4, c4 = (f & 15) * 4;
        float4 v = *(const float4*)(xrow + r * 64 + c4);
        *(float4*)(xS + r * 68 + c4) = v;
        uint2 pk = { pack_rne(v.x, v.y), pack_rne(v.z, v.w) };
        *(uint2*)(xbS + r * 72 + c4) = pk;
    }
    for (int e = t; e < 512; e += 256) {
        int ci = e >> 3, j = e & 7;
        WfT[j * 68 + ci] = Wf[e];
        WgT[j * 68 + ci] = Wg[e];
    }
    __syncthreads();

    const int w = t >> 6, lane = t & 63, ml = lane & 15, quad = lane >> 4;

    // ---- V^T via MFMA: wave w owns couts w*16..w*16+15
    {
        s16x8 a0, a1;   // A[m=cout][k=cin] = Wh[cin][cout]
        #pragma unroll
        for (int j = 0; j < 8; ++j) {
            a0[j] = (short)f2bf(Wh[(quad * 8 + j) * 64 + w * 16 + ml]);
            a1[j] = (short)f2bf(Wh[(32 + quad * 8 + j) * 64 + w * 16 + ml]);
        }
        #pragma unroll
        for (int nf = 0; nf < 2; ++nf) {
            int tok = nf * 16 + ml;
            s16x8 b0 = *(const s16x8*)(xbS + tok * 72 + quad * 8);
            s16x8 b1 = *(const s16x8*)(xbS + tok * 72 + 32 + quad * 8);
            f32x4 cc = __builtin_amdgcn_mfma_f32_16x16x32_bf16(a0, b0, (f32x4){0.f,0.f,0.f,0.f}, 0, 0, 0);
            cc = __builtin_amdgcn_mfma_f32_16x16x32_bf16(a1, b1, cc, 0, 0, 0);
            #pragma unroll
            for (int reg = 0; reg < 4; ++reg) {
                int cout = w * 16 + quad * 4 + reg;
                vtS[cout * 40 + nf * 16 + ml] = f2bf(cc[reg] + bh[cout]);
            }
        }
    }

    // ---- q/k: thread (r = t>>3, j = t&7): fp32 VALU + Dekker pack
    {
        int r = t >> 3, j = t & 7;
        float q = bf_[j], k = bg[j];
        for (int ci = 0; ci < 64; ci += 4) {
            float4 x4 = *(const float4*)(xS + r * 68 + ci);
            float4 wf4 = *(const float4*)(WfT + j * 68 + ci);
            float4 wg4 = *(const float4*)(WgT + j * 68 + ci);
            q += x4.x * wf4.x + x4.y * wf4.y + x4.z * wf4.z + x4.w * wf4.w;
            k += x4.x * wg4.x + x4.y * wg4.y + x4.z * wg4.z + x4.w * wg4.w;
        }
        unsigned short qh, kh;
        float qres = bf_split(q, qh);
        float kres = bf_split(k, kh);
        unsigned short ql = f2bf(qres), kl = f2bf(kres);
        size_t qbase = ((size_t)b * NTOK + n0 + r) * 32;
        Qp[qbase + j]      = qh;
        Qp[qbase + 8 + j]  = ql;
        Qp[qbase + 16 + j] = qh;
        Qp[qbase + 24 + j] = 0;
        size_t kbase = ((size_t)b * NTOK + n0 + r) * 16;
        Kp[kbase + j]     = kh;
        Kp[kbase + 8 + j] = kl;
    }
    __syncthreads();

    // ---- coalesced vT store
    {
        int c_ = t >> 2, chunk = t & 3;
        uint4 v = *(const uint4*)(vtS + c_ * 40 + chunk * 8);
        *(uint4*)(vTg + ((size_t)b * CCH + c_) * NTOK + n0 + chunk * 8) = v;
    }
}

// ---------------------------------------------------------------------------
// Attention — BARRIER-FREE K-loop. grid = B*64*KSPLIT = 512 blocks, 256 thr.
// Each wave owns TPW=8 DISJOINT 64-key tiles and covers ALL 64 queries x all
// 64 channels -> no inter-wave sharing in the loop, zero __syncthreads.
// K resident in static LDS (one init barrier). V A-frags loaded per-wave
// straight from global (L2/LLC), issued ~600 cycles before use.
// S^T-MFMA with permuted key rows lands exp(P) directly in PV B-layout.
// Epilogue: LDS fp32 reduction across the 4 waves, bf16 Opart per split.
// ---------------------------------------------------------------------------
__global__ __launch_bounds__(256, 2) void attn_kernel(
    const unsigned short* __restrict__ Qp,
    const unsigned short* __restrict__ Kp,
    const unsigned short* __restrict__ vTg,
    unsigned short* __restrict__ Opart,
    float* __restrict__ lpart)
{
    __shared__ unsigned short KC[KPB * 16];   // [key][kh8|kl8], 64 KB

    const int t = threadIdx.x;
    const int blk = blockIdx.x;
    const int b = blk >> 7;              // 128 blocks per batch (64 qt x 2 ks)
    const int qt = (blk >> 1) & 63;
    const int ks = blk & 1;
    const int m0 = qt * 64;
    const int kb0 = ks * KPB;
    const int w = t >> 6, lane = t & 63;
    const int ml = lane & 15, quad = lane >> 4;

    const unsigned short* qpb = Qp + (size_t)b * NTOK * 32;
    const unsigned short* kpb = Kp + (size_t)b * NTOK * 16;
    const unsigned short* vtb = vTg + (size_t)b * CCH * NTOK;

    // stage KC: all 2048 keys of this split (the only loop-external barrier)
    for (int kk = t; kk < KPB; kk += 256) {
        const unsigned short* src = kpb + (size_t)(kb0 + kk) * 16;
        *(uint4*)(&KC[kk * 16])     = *(const uint4*)(src);
        *(uint4*)(&KC[kk * 16 + 8]) = *(const uint4*)(src + 8);
    }

    // Q B-frags for ALL 4 query groups (wave covers 64 queries)
    s16x8 qf[4];
    #pragma unroll
    for (int qg = 0; qg < 4; ++qg)
        qf[qg] = *(const s16x8*)(qpb + (size_t)(m0 + qg * 16 + ml) * 32 + quad * 8);

    const int keyA = 8 * (ml >> 2) + (ml & 3);   // permuted key row
    const int khsel = (quad == 2) ? 8 : 0;       // quad0,1,3->kh  quad2->kl
                                                 // (quad3 x Q's zero slice)
    s16x8 ones;
    #pragma unroll
    for (int i = 0; i < 8; ++i) ones[i] = (short)0x3F80;

    f32x4 o[4][4];    // [cg][qg] : O^T[ch cg*16+quad*4+r][query qg*16+ml]
    f32x4 lac[4];
    #pragma unroll
    for (int cg = 0; cg < 4; ++cg)
        #pragma unroll
        for (int qg = 0; qg < 4; ++qg) o[cg][qg] = (f32x4){0.f,0.f,0.f,0.f};
    #pragma unroll
    for (int qg = 0; qg < 4; ++qg) lac[qg] = (f32x4){0.f,0.f,0.f,0.f};
    const f32x4 zz = {0.f, 0.f, 0.f, 0.f};

    __syncthreads();   // KC visible; no more barriers until epilogue

    // preload K frags for this wave's first tile
    const int tile0 = w * TPW;
    s16x8 kf0 = *(const s16x8*)(&KC[(tile0 * 64 + keyA) * 16 + khsel]);
    s16x8 kf1 = *(const s16x8*)(&KC[(tile0 * 64 + keyA + 4) * 16 + khsel]);
    s16x8 kf2 = *(const s16x8*)(&KC[(tile0 * 64 + 32 + keyA) * 16 + khsel]);
    s16x8 kf3 = *(const s16x8*)(&KC[(tile0 * 64 + 36 + keyA) * 16 + khsel]);

    for (int i = 0; i < TPW; ++i) {
        const int tile = w * TPW + i;
        const int kb = kb0 + tile * 64;

        // V A-frags for this tile (global, consumed ~600 cyc later)
        s16x8 vf[4][2];
        #pragma unroll
        for (int cg = 0; cg < 4; ++cg) {
            const unsigned short* vr = vtb + (size_t)(cg * 16 + ml) * NTOK + kb + quad * 8;
            vf[cg][0] = *(const s16x8*)(vr);
            vf[cg][1] = *(const s16x8*)(vr + 32);
        }
        // prefetch K frags for next tile (static LDS, no barrier)
        const int tn = (i + 1 < TPW) ? tile + 1 : tile0;
        s16x8 kn0 = *(const s16x8*)(&KC[(tn * 64 + keyA) * 16 + khsel]);
        s16x8 kn1 = *(const s16x8*)(&KC[(tn * 64 + keyA + 4) * 16 + khsel]);
        s16x8 kn2 = *(const s16x8*)(&KC[(tn * 64 + 32 + keyA) * 16 + khsel]);
        s16x8 kn3 = *(const s16x8*)(&KC[(tn * 64 + 36 + keyA) * 16 + khsel]);

        // S + softmax numerator for all 4 query groups -> register P frags
        union { unsigned u[4]; s16x8 h; } P0[4], P1[4];
        #pragma unroll
        for (int qg = 0; qg < 4; ++qg) {
            f32x4 sA0 = __builtin_amdgcn_mfma_f32_16x16x32_bf16(kf0, qf[qg], zz, 0, 0, 0);
            f32x4 sB0 = __builtin_amdgcn_mfma_f32_16x16x32_bf16(kf1, qf[qg], zz, 0, 0, 0);
            f32x4 sA1 = __builtin_amdgcn_mfma_f32_16x16x32_bf16(kf2, qf[qg], zz, 0, 0, 0);
            f32x4 sB1 = __builtin_amdgcn_mfma_f32_16x16x32_bf16(kf3, qf[qg], zz, 0, 0, 0);
            P0[qg].u[0] = pack_trunc(pexp(sA0[0]), pexp(sA0[1]));
            P0[qg].u[1] = pack_trunc(pexp(sA0[2]), pexp(sA0[3]));
            P0[qg].u[2] = pack_trunc(pexp(sB0[0]), pexp(sB0[1]));
            P0[qg].u[3] = pack_trunc(pexp(sB0[2]), pexp(sB0[3]));
            P1[qg].u[0] = pack_trunc(pexp(sA1[0]), pexp(sA1[1]));
            P1[qg].u[1] = pack_trunc(pexp(sA1[2]), pexp(sA1[3]));
            P1[qg].u[2] = pack_trunc(pexp(sB1[0]), pexp(sB1[1]));
            P1[qg].u[3] = pack_trunc(pexp(sB1[2]), pexp(sB1[3]));
        }
        kf0 = kn0; kf1 = kn1; kf2 = kn2; kf3 = kn3;

        // l += ones * P
        #pragma unroll
        for (int qg = 0; qg < 4; ++qg) {
            lac[qg] = __builtin_amdgcn_mfma_f32_16x16x32_bf16(ones, P0[qg].h, lac[qg], 0, 0, 0);
            lac[qg] = __builtin_amdgcn_mfma_f32_16x16x32_bf16(ones, P1[qg].h, lac[qg], 0, 0, 0);
        }
        // O^T += V^T * P
        #pragma unroll
        for (int cg = 0; cg < 4; ++cg)
            #pragma unroll
            for (int qg = 0; qg < 4; ++qg) {
                o[cg][qg] = __builtin_amdgcn_mfma_f32_16x16x32_bf16(vf[cg][0], P0[qg].h, o[cg][qg], 0, 0, 0);
                o[cg][qg] = __builtin_amdgcn_mfma_f32_16x16x32_bf16(vf[cg][1], P1[qg].h, o[cg][qg], 0, 0, 0);
            }
    }

    // ---- epilogue: fp32 reduction across 4 waves via LDS (reuse KC)
    float* OL = (float*)KC;          // [64 query][68], 17.4 KB
    float* lL = OL + 64 * 68;        // [64]
    #pragma unroll
    for (int r = 0; r < 4; ++r) {
        __syncthreads();
        if (w == r) {
            #pragma unroll
            for (int cg = 0; cg < 4; ++cg)
                #pragma unroll
                for (int qg = 0; qg < 4; ++qg) {
                    f32x4* p = (f32x4*)(&OL[(qg * 16 + ml) * 68 + cg * 16 + quad * 4]);
                    if (r == 0) *p = o[cg][qg];
                    else {
                        f32x4 v = *p;
                        v[0] += o[cg][qg][0]; v[1] += o[cg][qg][1];
                        v[2] += o[cg][qg][2]; v[3] += o[cg][qg][3];
                        *p = v;
                    }
                }
            if (quad == 0) {
                #pragma unroll
                for (int qg = 0; qg < 4; ++qg) {
                    if (r == 0) lL[qg * 16 + ml] = lac[qg][0];
                    else        lL[qg * 16 + ml] += lac[qg][0];
                }
            }
        }
    }
    __syncthreads();

    // writeout: Opart bf16 + lpart
    {
        int q = t >> 2, c0 = (t & 3) * 16;
        alignas(16) unsigned short us[16];
        #pragma unroll
        for (int k = 0; k < 16; ++k) us[k] = f2bf(OL[q * 68 + c0 + k]);
        size_t obase = ((size_t)ks * (BATCH * NTOK) + (size_t)b * NTOK + m0 + q) * 64 + c0;
        *(uint4*)(Opart + obase)     = *(uint4*)(us);
        *(uint4*)(Opart + obase + 8) = *(uint4*)(us + 8);
    }
    if (t < 64)
        lpart[ks * (BATCH * NTOK) + b * NTOK + m0 + t] = lL[t];
}

// ---------------------------------------------------------------------------
// Combine: out = gamma * (sum_s O_s) / (sum_s l_s) + x.  1024 blocks x 256.
// ---------------------------------------------------------------------------
__global__ __launch_bounds__(256) void combine_kernel(
    const float* __restrict__ xg,
    const unsigned short* __restrict__ Opart,
    const float* __restrict__ lpart,
    const float* __restrict__ gammaPtr,
    float* __restrict__ out)
{
    const int i4 = blockIdx.x * 256 + threadIdx.x;
    const int base = i4 * 4;
    const int tok = base >> 6;

    float lsum = 0.f;
    #pragma unroll
    for (int s = 0; s < KSPLIT; ++s)
        lsum += lpart[s * (BATCH * NTOK) + tok];

    float o0 = 0.f, o1 = 0.f, o2 = 0.f, o3 = 0.f;
    #pragma unroll
    for (int s = 0; s < KSPLIT; ++s) {
        uint2 u = *(const uint2*)(Opart + (size_t)s * (BATCH * NTOK * 64) + base);
        o0 += bf2f((unsigned short)(u.x & 0xFFFF));
        o1 += bf2f((unsigned short)(u.x >> 16));
        o2 += bf2f((unsigned short)(u.y & 0xFFFF));
        o3 += bf2f((unsigned short)(u.y >> 16));
    }
    const float4 x4 = *(const float4*)(xg + base);
    const float gi = gammaPtr[0] / lsum;
    float4 r;
    r.x = gi * o0 + x4.x;
    r.y = gi * o1 + x4.y;
    r.z = gi * o2 + x4.z;
    r.w = gi * o3 + x4.w;
    *(float4*)(out + base) = r;
}

extern "C" void kernel_launch(void* const* d_in, const int* in_sizes, int n_in,
                              void* d_out, int out_size, void* d_ws, size_t ws_size,
                              hipStream_t stream) {
    const float* x  = (const float*)d_in[0];
    const float* Wf = (const float*)d_in[1];
    const float* bf = (const float*)d_in[2];
    const float* Wg = (const float*)d_in[3];
    const float* bg = (const float*)d_in[4];
    const float* Wh = (const float*)d_in[5];
    const float* bh = (const float*)d_in[6];
    const float* gamma = (const float*)d_in[7];
    float* out = (float*)d_out;

    // ws: Qp 1MB @0 | Kp 512KB @1MB | vT 2MB @2MB | Opart 4MB @4MB | lpart @8MB
    char* ws = (char*)d_ws;
    unsigned short* Qp    = (unsigned short*)ws;
    unsigned short* Kp    = (unsigned short*)(ws + (1u << 20));
    unsigned short* vTg   = (unsigned short*)(ws + (2u << 20));
    unsigned short* Opart = (unsigned short*)(ws + (4u << 20));
    float*          lpart = (float*)(ws + (8u << 20));

    proj_kernel<<<BATCH * 128, 256, 0, stream>>>(x, Wf, bf, Wg, bg, Wh, bh,
                                                 Qp, Kp, vTg);
    attn_kernel<<<BATCH * 64 * KSPLIT, 256, 0, stream>>>(Qp, Kp, vTg, Opart, lpart);
    combine_kernel<<<(BATCH * NTOK * CCH) / 1024, 256, 0, stream>>>(x, Opart, lpart, gamma, out);
}

// Round 9
// 100.179 us; speedup vs baseline: 1.2582x; 1.1088x over previous
//
#include <hip/hip_runtime.h>
#include <hip/hip_bf16.h>

// Problem: B=4, H=W=64 -> N=4096 tokens, C=64, d=8
#define BATCH 4
#define NTOK 4096
#define CCH 64
#define KSPLIT 2
#define KPB (NTOK / KSPLIT)   // 2048 keys per attn block
#define NTILE (KPB / 64)      // 32 key tiles per block
#define TPW (NTILE / 4)       // 8 tiles per wave (waves own disjoint tiles)

// Schraudolph-to-bf16: p_bits16 = (int)(s*128*log2e + SBIAS), computed with
// the scale folded into Q (proj) and the bias folded into the S-MFMA C-seed.
#define QSCALE 184.66496523f   // 128 * log2(e)
#define SBIAS  16251.0f        // 127*128 - 5.0 (optimal Schraudolph bias, 7-bit mantissa)

typedef short s16x8 __attribute__((ext_vector_type(8)));
typedef float f32x4 __attribute__((ext_vector_type(4)));

static __device__ __forceinline__ unsigned short f2bf(float f) {
    union { __hip_bfloat16 h; unsigned short u; } cv;
    cv.h = __float2bfloat16(f);
    return cv.u;
}
static __device__ __forceinline__ float bf2f(unsigned short u) {
    union { unsigned int u; float f; } c; c.u = ((unsigned)u) << 16;
    return c.f;
}
static __device__ __forceinline__ float bf_split(float f, unsigned short& h) {
    h = f2bf(f);
    return f - bf2f(h);
}
static __device__ __forceinline__ unsigned pack_rne(float a, float b) {
    return ((unsigned)f2bf(b) << 16) | f2bf(a);
}
// pack two Schraudolph bf16 bit-patterns (values in (0, 32768))
static __device__ __forceinline__ unsigned pack_bits(float a, float b) {
    return ((unsigned)(int)b << 16) | (unsigned)(int)a;
}

// ---------------------------------------------------------------------------
// Projections.
//   Qpack[b][n][32] bf16 = [qh|ql|qh|0]  with q PRE-SCALED by QSCALE
//   Kpack[b][n][16] bf16 = [kh|kl]
//   vT[b][c][n] bf16 — V^T via MFMA (bf16 x staged once in LDS)
// grid: B*128 blocks (32-token tiles), 256 threads.
// ---------------------------------------------------------------------------
__global__ __launch_bounds__(256) void proj_kernel(
    const float* __restrict__ xg,
    const float* __restrict__ Wf, const float* __restrict__ bf_,
    const float* __restrict__ Wg, const float* __restrict__ bg,
    const float* __restrict__ Wh, const float* __restrict__ bh,
    unsigned short* __restrict__ Qp, unsigned short* __restrict__ Kp,
    unsigned short* __restrict__ vTg)
{
    __shared__ float xS[32 * 68];            // fp32 x tile (q/k path)
    __shared__ unsigned short xbS[32 * 72];  // bf16 x tile, 64 ch/row
    __shared__ float WfT[8 * 68];
    __shared__ float WgT[8 * 68];
    __shared__ unsigned short vtS[64 * 40];  // V^T tile [cout][32 tok + pad]

    const int t = threadIdx.x;
    const int b = blockIdx.x >> 7;
    const int n0 = (blockIdx.x & 127) * 32;

    const float* xrow = xg + ((size_t)b * NTOK + n0) * CCH;
    for (int f = t; f < 512; f += 256) {
        int r = f >> 4, c4 = (f & 15) * 4;
        float4 v = *(const float4*)(xrow + r * 64 + c4);
        *(float4*)(xS + r * 68 + c4) = v;
        uint2 pk = { pack_rne(v.x, v.y), pack_rne(v.z, v.w) };
        *(uint2*)(xbS + r * 72 + c4) = pk;
    }
    for (int e = t; e < 512; e += 256) {
        int ci = e >> 3, j = e & 7;
        WfT[j * 68 + ci] = Wf[e];
        WgT[j * 68 + ci] = Wg[e];
    }
    __syncthreads();

    const int w = t >> 6, lane = t & 63, ml = lane & 15, quad = lane >> 4;

    // ---- V^T via MFMA: wave w owns couts w*16..w*16+15
    {
        s16x8 a0, a1;   // A[m=cout][k=cin] = Wh[cin][cout]
        #pragma unroll
        for (int j = 0; j < 8; ++j) {
            a0[j] = (short)f2bf(Wh[(quad * 8 + j) * 64 + w * 16 + ml]);
            a1[j] = (short)f2bf(Wh[(32 + quad * 8 + j) * 64 + w * 16 + ml]);
        }
        #pragma unroll
        for (int nf = 0; nf < 2; ++nf) {
            int tok = nf * 16 + ml;
            s16x8 b0 = *(const s16x8*)(xbS + tok * 72 + quad * 8);
            s16x8 b1 = *(const s16x8*)(xbS + tok * 72 + 32 + quad * 8);
            f32x4 cc = __builtin_amdgcn_mfma_f32_16x16x32_bf16(a0, b0, (f32x4){0.f,0.f,0.f,0.f}, 0, 0, 0);
            cc = __builtin_amdgcn_mfma_f32_16x16x32_bf16(a1, b1, cc, 0, 0, 0);
            #pragma unroll
            for (int reg = 0; reg < 4; ++reg) {
                int cout = w * 16 + quad * 4 + reg;
                vtS[cout * 40 + nf * 16 + ml] = f2bf(cc[reg] + bh[cout]);
            }
        }
    }

    // ---- q/k: thread (r = t>>3, j = t&7): fp32 VALU + Dekker pack
    {
        int r = t >> 3, j = t & 7;
        float q = bf_[j], k = bg[j];
        for (int ci = 0; ci < 64; ci += 4) {
            float4 x4 = *(const float4*)(xS + r * 68 + ci);
            float4 wf4 = *(const float4*)(WfT + j * 68 + ci);
            float4 wg4 = *(const float4*)(WgT + j * 68 + ci);
            q += x4.x * wf4.x + x4.y * wf4.y + x4.z * wf4.z + x4.w * wf4.w;
            k += x4.x * wg4.x + x4.y * wg4.y + x4.z * wg4.z + x4.w * wg4.w;
        }
        q *= QSCALE;   // fold Schraudolph scale (128*log2e) into Q
        unsigned short qh, kh;
        float qres = bf_split(q, qh);
        float kres = bf_split(k, kh);
        unsigned short ql = f2bf(qres), kl = f2bf(kres);
        size_t qbase = ((size_t)b * NTOK + n0 + r) * 32;
        Qp[qbase + j]      = qh;
        Qp[qbase + 8 + j]  = ql;
        Qp[qbase + 16 + j] = qh;
        Qp[qbase + 24 + j] = 0;
        size_t kbase = ((size_t)b * NTOK + n0 + r) * 16;
        Kp[kbase + j]     = kh;
        Kp[kbase + 8 + j] = kl;
    }
    __syncthreads();

    // ---- coalesced vT store
    {
        int c_ = t >> 2, chunk = t & 3;
        uint4 v = *(const uint4*)(vtS + c_ * 40 + chunk * 8);
        *(uint4*)(vTg + ((size_t)b * CCH + c_) * NTOK + n0 + chunk * 8) = v;
    }
}

// ---------------------------------------------------------------------------
// Attention — barrier-free K-loop, NO v_exp (Schraudolph bits).
// grid = B*64*KSPLIT = 512 blocks, 256 thr, 2 blocks/CU.
// Each wave owns TPW=8 disjoint 64-key tiles, covers all 64 q x 64 ch.
// S-MFMA accumulator seeded with SBIAS -> p_bf16bits = (int)s, full-rate.
// K resident in static LDS; V A-frags straight from global/L2.
// ---------------------------------------------------------------------------
__global__ __launch_bounds__(256, 2) void attn_kernel(
    const unsigned short* __restrict__ Qp,
    const unsigned short* __restrict__ Kp,
    const unsigned short* __restrict__ vTg,
    unsigned short* __restrict__ Opart,
    float* __restrict__ lpart)
{
    __shared__ unsigned short KC[KPB * 16];   // [key][kh8|kl8], 64 KB

    const int t = threadIdx.x;
    const int blk = blockIdx.x;
    const int b = blk >> 7;
    const int qt = (blk >> 1) & 63;
    const int ks = blk & 1;
    const int m0 = qt * 64;
    const int kb0 = ks * KPB;
    const int w = t >> 6, lane = t & 63;
    const int ml = lane & 15, quad = lane >> 4;

    const unsigned short* qpb = Qp + (size_t)b * NTOK * 32;
    const unsigned short* kpb = Kp + (size_t)b * NTOK * 16;
    const unsigned short* vtb = vTg + (size_t)b * CCH * NTOK;

    for (int kk = t; kk < KPB; kk += 256) {
        const unsigned short* src = kpb + (size_t)(kb0 + kk) * 16;
        *(uint4*)(&KC[kk * 16])     = *(const uint4*)(src);
        *(uint4*)(&KC[kk * 16 + 8]) = *(const uint4*)(src + 8);
    }

    s16x8 qf[4];
    #pragma unroll
    for (int qg = 0; qg < 4; ++qg)
        qf[qg] = *(const s16x8*)(qpb + (size_t)(m0 + qg * 16 + ml) * 32 + quad * 8);

    const int keyA = 8 * (ml >> 2) + (ml & 3);   // permuted key row
    const int khsel = (quad == 2) ? 8 : 0;       // quad0,1,3->kh  quad2->kl

    s16x8 ones;
    #pragma unroll
    for (int i = 0; i < 8; ++i) ones[i] = (short)0x3F80;

    f32x4 o[4][4];
    f32x4 lac[4];
    #pragma unroll
    for (int cg = 0; cg < 4; ++cg)
        #pragma unroll
        for (int qg = 0; qg < 4; ++qg) o[cg][qg] = (f32x4){0.f,0.f,0.f,0.f};
    #pragma unroll
    for (int qg = 0; qg < 4; ++qg) lac[qg] = (f32x4){0.f,0.f,0.f,0.f};
    const f32x4 sb = {SBIAS, SBIAS, SBIAS, SBIAS};   // Schraudolph bias seed

    __syncthreads();   // KC visible; no more barriers until epilogue

    const int tile0 = w * TPW;
    s16x8 kf0 = *(const s16x8*)(&KC[(tile0 * 64 + keyA) * 16 + khsel]);
    s16x8 kf1 = *(const s16x8*)(&KC[(tile0 * 64 + keyA + 4) * 16 + khsel]);
    s16x8 kf2 = *(const s16x8*)(&KC[(tile0 * 64 + 32 + keyA) * 16 + khsel]);
    s16x8 kf3 = *(const s16x8*)(&KC[(tile0 * 64 + 36 + keyA) * 16 + khsel]);

    for (int i = 0; i < TPW; ++i) {
        const int tile = w * TPW + i;
        const int kb = kb0 + tile * 64;

        // V A-frags for this tile (global/L2, consumed after softmax chain)
        s16x8 vf[4][2];
        #pragma unroll
        for (int cg = 0; cg < 4; ++cg) {
            const unsigned short* vr = vtb + (size_t)(cg * 16 + ml) * NTOK + kb + quad * 8;
            vf[cg][0] = *(const s16x8*)(vr);
            vf[cg][1] = *(const s16x8*)(vr + 32);
        }
        const int tn = (i + 1 < TPW) ? tile + 1 : tile0;
        s16x8 kn0 = *(const s16x8*)(&KC[(tn * 64 + keyA) * 16 + khsel]);
        s16x8 kn1 = *(const s16x8*)(&KC[(tn * 64 + keyA + 4) * 16 + khsel]);
        s16x8 kn2 = *(const s16x8*)(&KC[(tn * 64 + 32 + keyA) * 16 + khsel]);
        s16x8 kn3 = *(const s16x8*)(&KC[(tn * 64 + 36 + keyA) * 16 + khsel]);

        // S (bias-seeded) -> p bits via int cast; lands in PV B-layout
        union { unsigned u[4]; s16x8 h; } P0[4], P1[4];
        #pragma unroll
        for (int qg = 0; qg < 4; ++qg) {
            f32x4 sA0 = __builtin_amdgcn_mfma_f32_16x16x32_bf16(kf0, qf[qg], sb, 0, 0, 0);
            f32x4 sB0 = __builtin_amdgcn_mfma_f32_16x16x32_bf16(kf1, qf[qg], sb, 0, 0, 0);
            f32x4 sA1 = __builtin_amdgcn_mfma_f32_16x16x32_bf16(kf2, qf[qg], sb, 0, 0, 0);
            f32x4 sB1 = __builtin_amdgcn_mfma_f32_16x16x32_bf16(kf3, qf[qg], sb, 0, 0, 0);
            P0[qg].u[0] = pack_bits(sA0[0], sA0[1]);
            P0[qg].u[1] = pack_bits(sA0[2], sA0[3]);
            P0[qg].u[2] = pack_bits(sB0[0], sB0[1]);
            P0[qg].u[3] = pack_bits(sB0[2], sB0[3]);
            P1[qg].u[0] = pack_bits(sA1[0], sA1[1]);
            P1[qg].u[1] = pack_bits(sA1[2], sA1[3]);
            P1[qg].u[2] = pack_bits(sB1[0], sB1[1]);
            P1[qg].u[3] = pack_bits(sB1[2], sB1[3]);
        }
        kf0 = kn0; kf1 = kn1; kf2 = kn2; kf3 = kn3;

        // l += ones * P
        #pragma unroll
        for (int qg = 0; qg < 4; ++qg) {
            lac[qg] = __builtin_amdgcn_mfma_f32_16x16x32_bf16(ones, P0[qg].h, lac[qg], 0, 0, 0);
            lac[qg] = __builtin_amdgcn_mfma_f32_16x16x32_bf16(ones, P1[qg].h, lac[qg], 0, 0, 0);
        }
        // O^T += V^T * P
        #pragma unroll
        for (int cg = 0; cg < 4; ++cg)
            #pragma unroll
            for (int qg = 0; qg < 4; ++qg) {
                o[cg][qg] = __builtin_amdgcn_mfma_f32_16x16x32_bf16(vf[cg][0], P0[qg].h, o[cg][qg], 0, 0, 0);
                o[cg][qg] = __builtin_amdgcn_mfma_f32_16x16x32_bf16(vf[cg][1], P1[qg].h, o[cg][qg], 0, 0, 0);
            }
    }

    // ---- epilogue: fp32 reduction across 4 waves via LDS (reuse KC)
    float* OL = (float*)KC;          // [64 query][68]
    float* lL = OL + 64 * 68;        // [64]
    #pragma unroll
    for (int r = 0; r < 4; ++r) {
        __syncthreads();
        if (w == r) {
            #pragma unroll
            for (int cg = 0; cg < 4; ++cg)
                #pragma unroll
                for (int qg = 0; qg < 4; ++qg) {
                    f32x4* p = (f32x4*)(&OL[(qg * 16 + ml) * 68 + cg * 16 + quad * 4]);
                    if (r == 0) *p = o[cg][qg];
                    else {
                        f32x4 v = *p;
                        v[0] += o[cg][qg][0]; v[1] += o[cg][qg][1];
                        v[2] += o[cg][qg][2]; v[3] += o[cg][qg][3];
                        *p = v;
                    }
                }
            if (quad == 0) {
                #pragma unroll
                for (int qg = 0; qg < 4; ++qg) {
                    if (r == 0) lL[qg * 16 + ml] = lac[qg][0];
                    else        lL[qg * 16 + ml] += lac[qg][0];
                }
            }
        }
    }
    __syncthreads();

    {
        int q = t >> 2, c0 = (t & 3) * 16;
        alignas(16) unsigned short us[16];
        #pragma unroll
        for (int k = 0; k < 16; ++k) us[k] = f2bf(OL[q * 68 + c0 + k]);
        size_t obase = ((size_t)ks * (BATCH * NTOK) + (size_t)b * NTOK + m0 + q) * 64 + c0;
        *(uint4*)(Opart + obase)     = *(uint4*)(us);
        *(uint4*)(Opart + obase + 8) = *(uint4*)(us + 8);
    }
    if (t < 64)
        lpart[ks * (BATCH * NTOK) + b * NTOK + m0 + t] = lL[t];
}

// ---------------------------------------------------------------------------
// Combine: out = gamma * (sum_s O_s) / (sum_s l_s) + x.  1024 blocks x 256.
// ---------------------------------------------------------------------------
__global__ __launch_bounds__(256) void combine_kernel(
    const float* __restrict__ xg,
    const unsigned short* __restrict__ Opart,
    const float* __restrict__ lpart,
    const float* __restrict__ gammaPtr,
    float* __restrict__ out)
{
    const int i4 = blockIdx.x * 256 + threadIdx.x;
    const int base = i4 * 4;
    const int tok = base >> 6;

    float lsum = 0.f;
    #pragma unroll
    for (int s = 0; s < KSPLIT; ++s)
        lsum += lpart[s * (BATCH * NTOK) + tok];

    float o0 = 0.f, o1 = 0.f, o2 = 0.f, o3 = 0.f;
    #pragma unroll
    for (int s = 0; s < KSPLIT; ++s) {
        uint2 u = *(const uint2*)(Opart + (size_t)s * (BATCH * NTOK * 64) + base);
        o0 += bf2f((unsigned short)(u.x & 0xFFFF));
        o1 += bf2f((unsigned short)(u.x >> 16));
        o2 += bf2f((unsigned short)(u.y & 0xFFFF));
        o3 += bf2f((unsigned short)(u.y >> 16));
    }
    const float4 x4 = *(const float4*)(xg + base);
    const float gi = gammaPtr[0] / lsum;
    float4 r;
    r.x = gi * o0 + x4.x;
    r.y = gi * o1 + x4.y;
    r.z = gi * o2 + x4.z;
    r.w = gi * o3 + x4.w;
    *(float4*)(out + base) = r;
}

extern "C" void kernel_launch(void* const* d_in, const int* in_sizes, int n_in,
                              void* d_out, int out_size, void* d_ws, size_t ws_size,
                              hipStream_t stream) {
    const float* x  = (const float*)d_in[0];
    const float* Wf = (const float*)d_in[1];
    const float* bf = (const float*)d_in[2];
    const float* Wg = (const float*)d_in[3];
    const float* bg = (const float*)d_in[4];
    const float* Wh = (const float*)d_in[5];
    const float* bh = (const float*)d_in[6];
    const float* gamma = (const float*)d_in[7];
    float* out = (float*)d_out;

    // ws: Qp 1MB @0 | Kp 512KB @1MB | vT 2MB @2MB | Opart 4MB @4MB | lpart @8MB
    char* ws = (char*)d_ws;
    unsigned short* Qp    = (unsigned short*)ws;
    unsigned short* Kp    = (unsigned short*)(ws + (1u << 20));
    unsigned short* vTg   = (unsigned short*)(ws + (2u << 20));
    unsigned short* Opart = (unsigned short*)(ws + (4u << 20));
    float*          lpart = (float*)(ws + (8u << 20));

    proj_kernel<<<BATCH * 128, 256, 0, stream>>>(x, Wf, bf, Wg, bg, Wh, bh,
                                                 Qp, Kp, vTg);
    attn_kernel<<<BATCH * 64 * KSPLIT, 256, 0, stream>>>(Qp, Kp, vTg, Opart, lpart);
    combine_kernel<<<(BATCH * NTOK * CCH) / 1024, 256, 0, stream>>>(x, Opart, lpart, gamma, out);
}